// Round 2
// baseline (1260.644 us; speedup 1.0000x reference)
//
#include <hip/hip_runtime.h>
#include <math.h>

#define NB 128
#define C 2048
#define LATC 512
#define SLT 512
#define NSPLIT 16
#define CCHUNK (C / NSPLIT)   // 128

// -------- kernel 1: theta[n,l] = w_st[l,:]·st[n,:] + b_st[l];
//                    u[n,c] = sum_l theta[n,l] * w_lt[l,c]
__global__ __launch_bounds__(512) void k_theta_u(
    const float* __restrict__ st, const float* __restrict__ w_st,
    const float* __restrict__ b_st, const float* __restrict__ w_lt,
    float* __restrict__ theta, float* __restrict__ u)
{
    const int n = blockIdx.x;
    const int tid = threadIdx.x;
    __shared__ float st_s[C];     // 8 KB
    __shared__ float th_s[LATC];  // 2 KB

    for (int c = tid; c < C; c += 512) st_s[c] = st[(size_t)n * C + c];
    __syncthreads();

    // one theta output per thread (LATC == 512 == blockDim)
    {
        const float* wr = w_st + (size_t)tid * C;
        float acc = 0.f;
        #pragma unroll 8
        for (int c = 0; c < C; ++c) acc += wr[c] * st_s[c];
        acc += b_st[tid];
        th_s[tid] = acc;
        theta[(size_t)n * LATC + tid] = acc;
    }
    __syncthreads();

    // u: thread tid owns c = tid + {0,512,1024,1536}; coalesced w_lt reads
    float a0 = 0.f, a1 = 0.f, a2 = 0.f, a3 = 0.f;
    for (int l = 0; l < LATC; ++l) {
        const float t = th_s[l];
        const float* wr = w_lt + (size_t)l * C + tid;
        a0 += t * wr[0];
        a1 += t * wr[512];
        a2 += t * wr[1024];
        a3 += t * wr[1536];
    }
    float* un = u + (size_t)n * C + tid;
    un[0] = a0; un[512] = a1; un[1024] = a2; un[1536] = a3;
}

// -------- kernel 2: partial scores over a 128-channel chunk (streams lt)
__global__ __launch_bounds__(512) void k_scores(
    const float* __restrict__ lt, const float* __restrict__ u,
    float* __restrict__ part)
{
    const int b = blockIdx.x;          // n*NSPLIT + split
    const int n = b / NSPLIT;
    const int sp = b % NSPLIT;
    const int tid = threadIdx.x;       // t index 0..511
    __shared__ float u_s[CCHUNK];

    const int c0 = sp * CCHUNK;
    if (tid < CCHUNK) u_s[tid] = u[(size_t)n * C + c0 + tid];
    __syncthreads();

    const float* row = lt + (size_t)n * C * SLT + (size_t)c0 * SLT + tid;
    float acc = 0.f;
    #pragma unroll 8
    for (int c = 0; c < CCHUNK; ++c)
        acc += u_s[c] * row[(size_t)c * SLT];

    part[((size_t)b << 9) + tid] = acc;
}

// -------- kernel 3: reduce partials, scale, softmax over t -> p[n,t]
__global__ __launch_bounds__(512) void k_softmax(
    const float* __restrict__ part, float* __restrict__ p)
{
    const int n = blockIdx.x;
    const int tid = threadIdx.x;
    const int wave = tid >> 6, lane = tid & 63;
    __shared__ float red[8];

    float s = 0.f;
    #pragma unroll
    for (int k = 0; k < NSPLIT; ++k)
        s += part[(((size_t)n * NSPLIT + k) << 9) + tid];
    s *= 0.044194173824159216f;   // 1/sqrt(512)

    // block max
    float m = s;
    #pragma unroll
    for (int o = 32; o > 0; o >>= 1) m = fmaxf(m, __shfl_xor(m, o));
    if (lane == 0) red[wave] = m;
    __syncthreads();
    float mm = red[0];
    #pragma unroll
    for (int k = 1; k < 8; ++k) mm = fmaxf(mm, red[k]);
    __syncthreads();

    const float e = expf(s - mm);

    // block sum
    float t = e;
    #pragma unroll
    for (int o = 32; o > 0; o >>= 1) t += __shfl_xor(t, o);
    if (lane == 0) red[wave] = t;
    __syncthreads();
    float tot = 0.f;
    #pragma unroll
    for (int k = 0; k < 8; ++k) tot += red[k];

    p[(size_t)n * SLT + tid] = e / tot;
}

// -------- kernel 4: v[n,c] = sum_t lt[n,c,t] * p[n,t]  (streams lt again)
__global__ __launch_bounds__(256) void k_v(
    const float* __restrict__ lt, const float* __restrict__ p,
    float* __restrict__ v)
{
    const int b = blockIdx.x;            // 1024 blocks
    const int n = 127 - (b >> 3);        // reversed n order: reuse L3 tail
    const int chunk = b & 7;             // 8 chunks of 256 channels
    const int tid = threadIdx.x;
    const int wave = tid >> 6, lane = tid & 63;
    __shared__ float p_s[SLT];

    for (int t = tid; t < SLT; t += 256) p_s[t] = p[(size_t)n * SLT + t];
    __syncthreads();

    const float4 p0 = reinterpret_cast<const float4*>(p_s)[lane];
    const float4 p1 = reinterpret_cast<const float4*>(p_s)[lane + 64];

    const int c0 = chunk * 256;
    const float4* ltn = reinterpret_cast<const float4*>(lt + (size_t)n * C * SLT);

    for (int i = 0; i < 64; ++i) {
        const int c = c0 + (i << 2) + wave;
        const float4* row = ltn + (size_t)c * (SLT / 4);
        const float4 a = row[lane];
        const float4 bb = row[lane + 64];
        float d = a.x * p0.x + a.y * p0.y + a.z * p0.z + a.w * p0.w
                + bb.x * p1.x + bb.y * p1.y + bb.z * p1.z + bb.w * p1.w;
        #pragma unroll
        for (int o = 32; o > 0; o >>= 1) d += __shfl_xor(d, o);
        if (lane == 0) v[(size_t)n * C + c] = d;
    }
}

// -------- kernel 5: out_lat = w_g·v + b_g; final = w_out·out_lat + b_out; LN
__global__ __launch_bounds__(512) void k_out(
    const float* __restrict__ v, const float* __restrict__ w_g,
    const float* __restrict__ b_g, const float* __restrict__ w_out,
    const float* __restrict__ b_out, const float* __restrict__ ln_w,
    const float* __restrict__ ln_b, float* __restrict__ out)
{
    const int n = blockIdx.x;
    const int tid = threadIdx.x;
    const int wave = tid >> 6, lane = tid & 63;
    __shared__ float v_s[C];      // 8 KB
    __shared__ float ol_s[LATC];  // 2 KB
    __shared__ float redA[8], redB[8];

    for (int c = tid; c < C; c += 512) v_s[c] = v[(size_t)n * C + c];
    __syncthreads();

    {
        const float* wr = w_g + (size_t)tid * C;
        float acc = 0.f;
        #pragma unroll 8
        for (int c = 0; c < C; ++c) acc += wr[c] * v_s[c];
        ol_s[tid] = acc + b_g[tid];
    }
    __syncthreads();

    float f[4];
    #pragma unroll
    for (int k = 0; k < 4; ++k) {
        const int ch = tid + (k << 9);
        const float* wr = w_out + (size_t)ch * LATC;
        float acc = 0.f;
        #pragma unroll 8
        for (int l = 0; l < LATC; ++l) acc += wr[l] * ol_s[l];
        f[k] = acc + b_out[ch];
    }

    // LayerNorm over 2048 channels
    float s1 = f[0] + f[1] + f[2] + f[3];
    float s2 = f[0]*f[0] + f[1]*f[1] + f[2]*f[2] + f[3]*f[3];
    #pragma unroll
    for (int o = 32; o > 0; o >>= 1) {
        s1 += __shfl_xor(s1, o);
        s2 += __shfl_xor(s2, o);
    }
    if (lane == 0) { redA[wave] = s1; redB[wave] = s2; }
    __syncthreads();
    float S1 = 0.f, S2 = 0.f;
    #pragma unroll
    for (int k = 0; k < 8; ++k) { S1 += redA[k]; S2 += redB[k]; }

    const float mu = S1 * (1.0f / 2048.0f);
    const float var = S2 * (1.0f / 2048.0f) - mu * mu;
    const float rs = rsqrtf(var + 1e-5f);

    #pragma unroll
    for (int k = 0; k < 4; ++k) {
        const int ch = tid + (k << 9);
        out[(size_t)n * C + ch] = (f[k] - mu) * rs * ln_w[ch] + ln_b[ch];
    }
}

extern "C" void kernel_launch(void* const* d_in, const int* in_sizes, int n_in,
                              void* d_out, int out_size, void* d_ws, size_t ws_size,
                              hipStream_t stream)
{
    const float* st    = (const float*)d_in[0];
    const float* lt    = (const float*)d_in[1];
    const float* w_st  = (const float*)d_in[2];
    const float* b_st  = (const float*)d_in[3];
    const float* w_lt  = (const float*)d_in[4];
    // d_in[5] = b_lt: cancels in softmax, unused
    const float* w_g   = (const float*)d_in[6];
    const float* b_g   = (const float*)d_in[7];
    const float* w_out = (const float*)d_in[8];
    const float* b_out = (const float*)d_in[9];
    const float* ln_w  = (const float*)d_in[10];
    const float* ln_b  = (const float*)d_in[11];
    float* out = (float*)d_out;

    float* ws = (float*)d_ws;
    float* theta = ws;                       // 128*512
    float* u     = theta + NB * LATC;        // 128*2048
    float* part  = u + NB * C;               // 128*16*512
    float* p     = part + NB * NSPLIT * SLT; // 128*512
    float* v     = p + NB * SLT;             // 128*2048

    k_theta_u<<<NB, 512, 0, stream>>>(st, w_st, b_st, w_lt, theta, u);
    k_scores<<<NB * NSPLIT, 512, 0, stream>>>(lt, u, part);
    k_softmax<<<NB, 512, 0, stream>>>(part, p);
    k_v<<<NB * 8, 256, 0, stream>>>(lt, p, v);
    k_out<<<NB, 512, 0, stream>>>(v, w_g, b_g, w_out, b_out, ln_w, ln_b, out);
}